// Round 1
// baseline (878.501 us; speedup 1.0000x reference)
//
#include <hip/hip_runtime.h>
#include <math.h>

// GaussianAvatar: LBS skinning + tangent frames + gaussian param finalize.
// Sizes hard-coded from the reference.
namespace {
constexpr int kB = 32;
constexpr int kV = 25000;
constexpr int kJ = 20;
constexpr int kF = 50000;
constexpr int kN = 200000;

constexpr float kEps = 1e-8f;

// output layout (flat float32, concatenated in return order)
constexpr size_t OFF_MEANS  = 0;
constexpr size_t OFF_COLORS = (size_t)kB * kN * 3;                  // 19,200,000
constexpr size_t OFF_OPAC   = OFF_COLORS + (size_t)kB * kN * 3;     // 38,400,000
constexpr size_t OFF_SCALE  = OFF_OPAC + (size_t)kB * kN;           // 44,800,000
constexpr size_t OFF_ROT    = OFF_SCALE + (size_t)kB * kN * 3;      // 64,000,000

// workspace layout (bytes)
constexpr size_t WS_A   = 0;                         // B*J*12 floats = 30,720 B
constexpr size_t WS_VW  = 32768;                     // B*V*3 floats = 9,600,000 B
constexpr size_t WS_NRM = WS_VW + 9600000;           // B*V*3 floats = 9,600,000 B
}

// ---------------------------------------------------------------------------
// Kernel 1: per-batch joint transform chain. One thread per batch element.
// Computes A[b][j] = [Rg | tg] (3x4 row-major, 12 floats).
// ---------------------------------------------------------------------------
__global__ void jt_kernel(const float* __restrict__ pose,
                          const float* __restrict__ jr,
                          float* __restrict__ A) {
    int b = threadIdx.x;
    if (b >= kB) return;

    float Gr[9], Gt[3];
    for (int j = 0; j < kJ; ++j) {
        // Rodrigues
        float ax = pose[b * (kJ * 3) + j * 3 + 0];
        float ay = pose[b * (kJ * 3) + j * 3 + 1];
        float az = pose[b * (kJ * 3) + j * 3 + 2];
        float t2 = ax * ax + ay * ay + az * az + 1e-12f;
        float th = sqrtf(t2);
        float inv = 1.0f / th;
        float ux = ax * inv, uy = ay * inv, uz = az * inv;
        float s = sinf(th), c = cosf(th), oc = 1.0f - c;
        float R[9];
        R[0] = 1.0f + oc * (-(uy * uy + uz * uz));
        R[1] = -s * uz + oc * (ux * uy);
        R[2] =  s * uy + oc * (ux * uz);
        R[3] =  s * uz + oc * (ux * uy);
        R[4] = 1.0f + oc * (-(ux * ux + uz * uz));
        R[5] = -s * ux + oc * (uy * uz);
        R[6] = -s * uy + oc * (ux * uz);
        R[7] =  s * ux + oc * (uy * uz);
        R[8] = 1.0f + oc * (-(ux * ux + uy * uy));

        float jx = jr[j * 3 + 0], jy = jr[j * 3 + 1], jz = jr[j * 3 + 2];

        if (j == 0) {
            for (int k = 0; k < 9; ++k) Gr[k] = R[k];
            Gt[0] = jx; Gt[1] = jy; Gt[2] = jz;
        } else {
            float pjx = jr[(j - 1) * 3 + 0];
            float pjy = jr[(j - 1) * 3 + 1];
            float pjz = jr[(j - 1) * 3 + 2];
            float ltx = jx - pjx, lty = jy - pjy, ltz = jz - pjz;
            float nR[9], nT[3];
            for (int r = 0; r < 3; ++r) {
                float g0 = Gr[r * 3 + 0], g1 = Gr[r * 3 + 1], g2 = Gr[r * 3 + 2];
                nR[r * 3 + 0] = g0 * R[0] + g1 * R[3] + g2 * R[6];
                nR[r * 3 + 1] = g0 * R[1] + g1 * R[4] + g2 * R[7];
                nR[r * 3 + 2] = g0 * R[2] + g1 * R[5] + g2 * R[8];
                nT[r] = g0 * ltx + g1 * lty + g2 * ltz + Gt[r];
            }
            for (int k = 0; k < 9; ++k) Gr[k] = nR[k];
            Gt[0] = nT[0]; Gt[1] = nT[1]; Gt[2] = nT[2];
        }

        // A_j = [Gr | Gt - Gr @ jr_j]
        float tgx = Gt[0] - (Gr[0] * jx + Gr[1] * jy + Gr[2] * jz);
        float tgy = Gt[1] - (Gr[3] * jx + Gr[4] * jy + Gr[5] * jz);
        float tgz = Gt[2] - (Gr[6] * jx + Gr[7] * jy + Gr[8] * jz);
        float* Ao = A + ((size_t)b * kJ + j) * 12;
        Ao[0] = Gr[0]; Ao[1] = Gr[1]; Ao[2]  = Gr[2]; Ao[3]  = tgx;
        Ao[4] = Gr[3]; Ao[5] = Gr[4]; Ao[6]  = Gr[5]; Ao[7]  = tgy;
        Ao[8] = Gr[6]; Ao[9] = Gr[7]; Ao[10] = Gr[8]; Ao[11] = tgz;
    }
}

// ---------------------------------------------------------------------------
// Kernel 2: LBS skinning. grid (V-tiles, B). A[b] staged in LDS.
// ---------------------------------------------------------------------------
__global__ void skin_kernel(const float* __restrict__ A,
                            const float* __restrict__ sw,
                            const float* __restrict__ vt,
                            const float* __restrict__ scale,
                            const float* __restrict__ trans,
                            float* __restrict__ Vw) {
    int b = blockIdx.y;
    int v = blockIdx.x * blockDim.x + threadIdx.x;
    __shared__ float sA[kJ * 12];
    if (threadIdx.x < kJ * 12) sA[threadIdx.x] = A[(size_t)b * kJ * 12 + threadIdx.x];
    __syncthreads();
    if (v >= kV) return;

    float T[12];
#pragma unroll
    for (int k = 0; k < 12; ++k) T[k] = 0.0f;
#pragma unroll
    for (int j = 0; j < kJ; ++j) {
        float wj = sw[(size_t)v * kJ + j];
#pragma unroll
        for (int k = 0; k < 12; ++k) T[k] += wj * sA[j * 12 + k];
    }
    float x = vt[v * 3 + 0], y = vt[v * 3 + 1], z = vt[v * 3 + 2];
    float px = T[0] * x + T[1] * y + T[2]  * z + T[3];
    float py = T[4] * x + T[5] * y + T[6]  * z + T[7];
    float pz = T[8] * x + T[9] * y + T[10] * z + T[11];
    float s = scale[b];
    float tx = trans[b * 3 + 0], ty = trans[b * 3 + 1], tz = trans[b * 3 + 2];
    size_t o = ((size_t)b * kV + v) * 3;
    Vw[o + 0] = px * s + tx;
    Vw[o + 1] = py * s + ty;
    Vw[o + 2] = pz * s + tz;
}

// ---------------------------------------------------------------------------
// Kernel 3: face-normal scatter. grid (F-tiles, B). 9 atomics per face.
// ---------------------------------------------------------------------------
__global__ void fnorm_kernel(const float* __restrict__ Vw,
                             const int* __restrict__ faces,
                             float* __restrict__ nrm) {
    int b = blockIdx.y;
    int f = blockIdx.x * blockDim.x + threadIdx.x;
    if (f >= kF) return;
    int i0 = faces[f * 3 + 0];
    int i1 = faces[f * 3 + 1];
    int i2 = faces[f * 3 + 2];
    const float* base = Vw + (size_t)b * kV * 3;
    float ax = base[i0 * 3 + 0], ay = base[i0 * 3 + 1], az = base[i0 * 3 + 2];
    float bx = base[i1 * 3 + 0], by = base[i1 * 3 + 1], bz = base[i1 * 3 + 2];
    float cx = base[i2 * 3 + 0], cy = base[i2 * 3 + 1], cz = base[i2 * 3 + 2];
    float e1x = bx - ax, e1y = by - ay, e1z = bz - az;
    float e2x = cx - ax, e2y = cy - ay, e2z = cz - az;
    float fnx = e1y * e2z - e1z * e2y;
    float fny = e1z * e2x - e1x * e2z;
    float fnz = e1x * e2y - e1y * e2x;
    float* nb = nrm + (size_t)b * kV * 3;
    atomicAdd(&nb[i0 * 3 + 0], fnx);
    atomicAdd(&nb[i0 * 3 + 1], fny);
    atomicAdd(&nb[i0 * 3 + 2], fnz);
    atomicAdd(&nb[i1 * 3 + 0], fnx);
    atomicAdd(&nb[i1 * 3 + 1], fny);
    atomicAdd(&nb[i1 * 3 + 2], fnz);
    atomicAdd(&nb[i2 * 3 + 0], fnx);
    atomicAdd(&nb[i2 * 3 + 1], fny);
    atomicAdd(&nb[i2 * 3 + 2], fnz);
}

// ---------------------------------------------------------------------------
// Kernel 4: finalize per (b, n). Gathers Vw/nrm, builds frame, writes all
// five outputs.
// ---------------------------------------------------------------------------
__global__ void finalize_kernel(const float* __restrict__ Vw,
                                const float* __restrict__ nrm,
                                const int* __restrict__ vidx,
                                const float* __restrict__ poff,
                                const float* __restrict__ craw,
                                const float* __restrict__ oraw,
                                const float* __restrict__ lsc,
                                const float* __restrict__ quat,
                                float* __restrict__ out) {
    int b = blockIdx.y;
    int n = blockIdx.x * blockDim.x + threadIdx.x;
    if (n >= kN) return;

    int vi = vidx[n];
    size_t vo = ((size_t)b * kV + vi) * 3;
    float bx = Vw[vo + 0], by = Vw[vo + 1], bz = Vw[vo + 2];

    // normal (normalize accumulated face normals)
    float nx0 = nrm[vo + 0], ny0 = nrm[vo + 1], nz0 = nrm[vo + 2];
    float ninv = rsqrtf(nx0 * nx0 + ny0 * ny0 + nz0 * nz0 + 1e-12f);
    float nx = nx0 * ninv, ny = ny0 * ninv, nz = nz0 * ninv;

    // tangent: ref = |n.x|<0.9 ? (1,0,0) : (0,0,1); t = normalize(ref - dot*n)
    bool small = fabsf(nx) < 0.9f;
    float refx = small ? 1.0f : 0.0f;
    float refz = small ? 0.0f : 1.0f;
    float d = refx * nx + refz * nz;
    float tx0 = refx - d * nx, ty0 = -d * ny, tz0 = refz - d * nz;
    float tinv = rsqrtf(tx0 * tx0 + ty0 * ty0 + tz0 * tz0 + 1e-12f);
    float tx = tx0 * tinv, ty = ty0 * tinv, tz = tz0 * tinv;

    // bitangent = cross(n, t)
    float btx = ny * tz - nz * ty;
    float bty = nz * tx - nx * tz;
    float btz = nx * ty - ny * tx;

    // means = base + o0*t + o1*bt + o2*n
    float o0 = poff[n * 3 + 0], o1 = poff[n * 3 + 1], o2 = poff[n * 3 + 2];
    float mx = bx + o0 * tx + o1 * btx + o2 * nx;
    float my = by + o0 * ty + o1 * bty + o2 * ny;
    float mz = bz + o0 * tz + o1 * btz + o2 * nz;

    // frame matrix columns = (t, bt, n)  ->  rot_to_quat (branch-faithful)
    float r00 = tx, r01 = btx, r02 = nx;
    float r10 = ty, r11 = bty, r12 = ny;
    float r20 = tz, r21 = btz, r22 = nz;
    float tr = r00 + r11 + r22;
    float q0, q1, q2, q3;
    if (tr > 0.0f) {
        float s = sqrtf(fmaxf(tr + 1.0f, kEps)) * 2.0f;
        q0 = 0.25f * s;
        q1 = (r21 - r12) / s;
        q2 = (r02 - r20) / s;
        q3 = (r10 - r01) / s;
    } else if (r00 > r11 && r00 > r22) {
        float s = sqrtf(fmaxf(1.0f + r00 - r11 - r22, kEps)) * 2.0f;
        q0 = (r21 - r12) / s;
        q1 = 0.25f * s;
        q2 = (r01 + r10) / s;
        q3 = (r02 + r20) / s;
    } else if (r11 > r22) {
        float s = sqrtf(fmaxf(1.0f + r11 - r00 - r22, kEps)) * 2.0f;
        q0 = (r02 - r20) / s;
        q1 = (r01 + r10) / s;
        q2 = 0.25f * s;
        q3 = (r12 + r21) / s;
    } else {
        float s = sqrtf(fmaxf(1.0f + r22 - r00 - r11, kEps)) * 2.0f;
        q0 = (r10 - r01) / s;
        q1 = (r02 + r20) / s;
        q2 = (r12 + r21) / s;
        q3 = 0.25f * s;
    }
    float qinv = rsqrtf(q0 * q0 + q1 * q1 + q2 * q2 + q3 * q3 + 1e-12f);
    q0 *= qinv; q1 *= qinv; q2 *= qinv; q3 *= qinv;

    // local quaternion, normalized
    float lw = quat[(size_t)n * 4 + 0];
    float lx = quat[(size_t)n * 4 + 1];
    float ly = quat[(size_t)n * 4 + 2];
    float lz = quat[(size_t)n * 4 + 3];
    float linv = rsqrtf(lw * lw + lx * lx + ly * ly + lz * lz + 1e-12f);
    lw *= linv; lx *= linv; ly *= linv; lz *= linv;

    // quat_mul(fq, lq)
    float rw = q0 * lw - q1 * lx - q2 * ly - q3 * lz;
    float rx = q0 * lx + q1 * lw + q2 * lz - q3 * ly;
    float ry = q0 * ly - q1 * lz + q2 * lw + q3 * lx;
    float rz = q0 * lz + q1 * ly - q2 * lx + q3 * lw;

    // per-n params
    float c0 = 1.0f / (1.0f + expf(-craw[n * 3 + 0]));
    float c1 = 1.0f / (1.0f + expf(-craw[n * 3 + 1]));
    float c2 = 1.0f / (1.0f + expf(-craw[n * 3 + 2]));
    float op = 1.0f / (1.0f + expf(-oraw[n]));
    float s0 = fminf(fmaxf(expf(lsc[n * 3 + 0]), 0.0005f), 0.05f);
    float s1 = fminf(fmaxf(expf(lsc[n * 3 + 1]), 0.0005f), 0.05f);
    float s2 = fminf(fmaxf(expf(lsc[n * 3 + 2]), 0.0005f), 0.05f);

    size_t bn = (size_t)b * kN + n;
    out[OFF_MEANS + bn * 3 + 0] = mx;
    out[OFF_MEANS + bn * 3 + 1] = my;
    out[OFF_MEANS + bn * 3 + 2] = mz;
    out[OFF_COLORS + bn * 3 + 0] = c0;
    out[OFF_COLORS + bn * 3 + 1] = c1;
    out[OFF_COLORS + bn * 3 + 2] = c2;
    out[OFF_OPAC + bn] = op;
    out[OFF_SCALE + bn * 3 + 0] = s0;
    out[OFF_SCALE + bn * 3 + 1] = s1;
    out[OFF_SCALE + bn * 3 + 2] = s2;
    out[OFF_ROT + bn * 4 + 0] = rw;
    out[OFF_ROT + bn * 4 + 1] = rx;
    out[OFF_ROT + bn * 4 + 2] = ry;
    out[OFF_ROT + bn * 4 + 3] = rz;
}

extern "C" void kernel_launch(void* const* d_in, const int* in_sizes, int n_in,
                              void* d_out, int out_size, void* d_ws, size_t ws_size,
                              hipStream_t stream) {
    const float* pose  = (const float*)d_in[0];
    const float* trans = (const float*)d_in[1];
    const float* scale = (const float*)d_in[2];
    const float* vt    = (const float*)d_in[3];
    const float* sw    = (const float*)d_in[4];
    const float* jr    = (const float*)d_in[5];
    const float* poff  = (const float*)d_in[6];
    const float* craw  = (const float*)d_in[7];
    const float* oraw  = (const float*)d_in[8];
    const float* lsc   = (const float*)d_in[9];
    const float* quat  = (const float*)d_in[10];
    const int*   vidx  = (const int*)d_in[11];
    const int*   faces = (const int*)d_in[12];
    float* out = (float*)d_out;

    char* ws = (char*)d_ws;
    float* A   = (float*)(ws + WS_A);
    float* Vw  = (float*)(ws + WS_VW);
    float* nrm = (float*)(ws + WS_NRM);

    hipMemsetAsync(nrm, 0, (size_t)kB * kV * 3 * sizeof(float), stream);

    jt_kernel<<<1, 64, 0, stream>>>(pose, jr, A);

    dim3 g2((kV + 255) / 256, kB);
    skin_kernel<<<g2, 256, 0, stream>>>(A, sw, vt, scale, trans, Vw);

    dim3 g3((kF + 255) / 256, kB);
    fnorm_kernel<<<g3, 256, 0, stream>>>(Vw, faces, nrm);

    dim3 g4((kN + 255) / 256, kB);
    finalize_kernel<<<g4, 256, 0, stream>>>(Vw, nrm, vidx, poff, craw, oraw,
                                            lsc, quat, out);
}

// Round 2
// 324.554 us; speedup vs baseline: 2.7068x; 2.7068x over previous
//
#include <hip/hip_runtime.h>
#include <math.h>

// GaussianAvatar: LBS skinning + tangent frames + gaussian param finalize.
// R2: replaced atomic face-normal scatter (704us, 449MB HBM write traffic,
// 8.9% BW util) with a CSR vertex->face adjacency + dense gather.
namespace {
constexpr int kB = 32;
constexpr int kV = 25000;
constexpr int kJ = 20;
constexpr int kF = 50000;
constexpr int kN = 200000;

constexpr float kEps = 1e-8f;

// output layout (flat float32, concatenated in return order)
constexpr size_t OFF_MEANS  = 0;
constexpr size_t OFF_COLORS = (size_t)kB * kN * 3;
constexpr size_t OFF_OPAC   = OFF_COLORS + (size_t)kB * kN * 3;
constexpr size_t OFF_SCALE  = OFF_OPAC + (size_t)kB * kN;
constexpr size_t OFF_ROT    = OFF_SCALE + (size_t)kB * kN * 3;

// workspace layout (bytes)
constexpr size_t WS_A       = 0;                          // B*J*12 f = 30,720
constexpr size_t WS_VW      = 32768;                      // B*V*3 f = 9,600,000
constexpr size_t WS_NRM     = WS_VW + 9600000;            // B*V*3 f = 9,600,000
constexpr size_t WS_CNT     = WS_NRM + 9600000;           // V ints  = 100,000
constexpr size_t WS_OFFS    = WS_CNT + 100032;            // (V+1) ints = 100,004
constexpr size_t WS_ENTRIES = WS_OFFS + 100032;           // 3F ints = 600,000
// end ~ 20.03 MB
}

// ---------------------------------------------------------------------------
// CSR build: count, scan (one block), fill.
// ---------------------------------------------------------------------------
__global__ void count_kernel(const int* __restrict__ faces,
                             int* __restrict__ cnt) {
    int f = blockIdx.x * blockDim.x + threadIdx.x;
    if (f >= kF) return;
    atomicAdd(&cnt[faces[f * 3 + 0]], 1);
    atomicAdd(&cnt[faces[f * 3 + 1]], 1);
    atomicAdd(&cnt[faces[f * 3 + 2]], 1);
}

__global__ void scan_kernel(const int* __restrict__ cnt,
                            int* __restrict__ off) {
    // single workgroup, 1024 threads, 25 elements each (25600 >= 25000)
    __shared__ int partial[1024];
    int t = threadIdx.x;
    int lo = t * 25;
    int hi = min(lo + 25, kV);
    int s = 0;
    for (int i = lo; i < hi; ++i) s += cnt[i];
    partial[t] = s;
    __syncthreads();
    if (t == 0) {
        int acc = 0;
        for (int i = 0; i < 1024; ++i) {
            int v = partial[i];
            partial[i] = acc;
            acc += v;
        }
    }
    __syncthreads();
    int acc = partial[t];
    for (int i = lo; i < hi; ++i) {
        off[i] = acc;
        acc += cnt[i];
    }
    if (lo < kV && hi == kV) off[kV] = acc;  // total = 3F
}

__global__ void fill_kernel(const int* __restrict__ faces,
                            const int* __restrict__ off,
                            int* __restrict__ cursor,
                            int* __restrict__ entries) {
    int f = blockIdx.x * blockDim.x + threadIdx.x;
    if (f >= kF) return;
#pragma unroll
    for (int k = 0; k < 3; ++k) {
        int v = faces[f * 3 + k];
        int p = atomicAdd(&cursor[v], 1);
        entries[off[v] + p] = f;
    }
}

// ---------------------------------------------------------------------------
// Kernel 1: per-batch joint transform chain. One thread per batch element.
// ---------------------------------------------------------------------------
__global__ void jt_kernel(const float* __restrict__ pose,
                          const float* __restrict__ jr,
                          float* __restrict__ A) {
    int b = threadIdx.x;
    if (b >= kB) return;

    float Gr[9], Gt[3];
    for (int j = 0; j < kJ; ++j) {
        float ax = pose[b * (kJ * 3) + j * 3 + 0];
        float ay = pose[b * (kJ * 3) + j * 3 + 1];
        float az = pose[b * (kJ * 3) + j * 3 + 2];
        float t2 = ax * ax + ay * ay + az * az + 1e-12f;
        float th = sqrtf(t2);
        float inv = 1.0f / th;
        float ux = ax * inv, uy = ay * inv, uz = az * inv;
        float s = sinf(th), c = cosf(th), oc = 1.0f - c;
        float R[9];
        R[0] = 1.0f + oc * (-(uy * uy + uz * uz));
        R[1] = -s * uz + oc * (ux * uy);
        R[2] =  s * uy + oc * (ux * uz);
        R[3] =  s * uz + oc * (ux * uy);
        R[4] = 1.0f + oc * (-(ux * ux + uz * uz));
        R[5] = -s * ux + oc * (uy * uz);
        R[6] = -s * uy + oc * (ux * uz);
        R[7] =  s * ux + oc * (uy * uz);
        R[8] = 1.0f + oc * (-(ux * ux + uy * uy));

        float jx = jr[j * 3 + 0], jy = jr[j * 3 + 1], jz = jr[j * 3 + 2];

        if (j == 0) {
            for (int k = 0; k < 9; ++k) Gr[k] = R[k];
            Gt[0] = jx; Gt[1] = jy; Gt[2] = jz;
        } else {
            float pjx = jr[(j - 1) * 3 + 0];
            float pjy = jr[(j - 1) * 3 + 1];
            float pjz = jr[(j - 1) * 3 + 2];
            float ltx = jx - pjx, lty = jy - pjy, ltz = jz - pjz;
            float nR[9], nT[3];
            for (int r = 0; r < 3; ++r) {
                float g0 = Gr[r * 3 + 0], g1 = Gr[r * 3 + 1], g2 = Gr[r * 3 + 2];
                nR[r * 3 + 0] = g0 * R[0] + g1 * R[3] + g2 * R[6];
                nR[r * 3 + 1] = g0 * R[1] + g1 * R[4] + g2 * R[7];
                nR[r * 3 + 2] = g0 * R[2] + g1 * R[5] + g2 * R[8];
                nT[r] = g0 * ltx + g1 * lty + g2 * ltz + Gt[r];
            }
            for (int k = 0; k < 9; ++k) Gr[k] = nR[k];
            Gt[0] = nT[0]; Gt[1] = nT[1]; Gt[2] = nT[2];
        }

        float tgx = Gt[0] - (Gr[0] * jx + Gr[1] * jy + Gr[2] * jz);
        float tgy = Gt[1] - (Gr[3] * jx + Gr[4] * jy + Gr[5] * jz);
        float tgz = Gt[2] - (Gr[6] * jx + Gr[7] * jy + Gr[8] * jz);
        float* Ao = A + ((size_t)b * kJ + j) * 12;
        Ao[0] = Gr[0]; Ao[1] = Gr[1]; Ao[2]  = Gr[2]; Ao[3]  = tgx;
        Ao[4] = Gr[3]; Ao[5] = Gr[4]; Ao[6]  = Gr[5]; Ao[7]  = tgy;
        Ao[8] = Gr[6]; Ao[9] = Gr[7]; Ao[10] = Gr[8]; Ao[11] = tgz;
    }
}

// ---------------------------------------------------------------------------
// Kernel 2: LBS skinning. grid (V-tiles, B). A[b] staged in LDS.
// ---------------------------------------------------------------------------
__global__ void skin_kernel(const float* __restrict__ A,
                            const float* __restrict__ sw,
                            const float* __restrict__ vt,
                            const float* __restrict__ scale,
                            const float* __restrict__ trans,
                            float* __restrict__ Vw) {
    int b = blockIdx.y;
    int v = blockIdx.x * blockDim.x + threadIdx.x;
    __shared__ float sA[kJ * 12];
    if (threadIdx.x < kJ * 12) sA[threadIdx.x] = A[(size_t)b * kJ * 12 + threadIdx.x];
    __syncthreads();
    if (v >= kV) return;

    float T[12];
#pragma unroll
    for (int k = 0; k < 12; ++k) T[k] = 0.0f;
#pragma unroll
    for (int j = 0; j < kJ; ++j) {
        float wj = sw[(size_t)v * kJ + j];
#pragma unroll
        for (int k = 0; k < 12; ++k) T[k] += wj * sA[j * 12 + k];
    }
    float x = vt[v * 3 + 0], y = vt[v * 3 + 1], z = vt[v * 3 + 2];
    float px = T[0] * x + T[1] * y + T[2]  * z + T[3];
    float py = T[4] * x + T[5] * y + T[6]  * z + T[7];
    float pz = T[8] * x + T[9] * y + T[10] * z + T[11];
    float s = scale[b];
    float tx = trans[b * 3 + 0], ty = trans[b * 3 + 1], tz = trans[b * 3 + 2];
    size_t o = ((size_t)b * kV + v) * 3;
    Vw[o + 0] = px * s + tx;
    Vw[o + 1] = py * s + ty;
    Vw[o + 2] = pz * s + tz;
}

// ---------------------------------------------------------------------------
// Kernel 3: per-(b,v) face-normal gather via CSR adjacency. No atomics.
// Recomputes each face's cross product per corner (3x redundant, L2-resident
// reads) — trades ~144 MFLOP for 14.4M atomics.
// ---------------------------------------------------------------------------
__global__ void gather_normals_kernel(const float* __restrict__ Vw,
                                      const int* __restrict__ faces,
                                      const int* __restrict__ off,
                                      const int* __restrict__ entries,
                                      float* __restrict__ nrm) {
    int b = blockIdx.y;
    int v = blockIdx.x * blockDim.x + threadIdx.x;
    if (v >= kV) return;
    const float* base = Vw + (size_t)b * kV * 3;
    float sx = 0.0f, sy = 0.0f, sz = 0.0f;
    int e0 = off[v], e1 = off[v + 1];
    for (int e = e0; e < e1; ++e) {
        int f = entries[e];
        int i0 = faces[f * 3 + 0];
        int i1 = faces[f * 3 + 1];
        int i2 = faces[f * 3 + 2];
        float ax = base[i0 * 3 + 0], ay = base[i0 * 3 + 1], az = base[i0 * 3 + 2];
        float bx = base[i1 * 3 + 0], by = base[i1 * 3 + 1], bz = base[i1 * 3 + 2];
        float cx = base[i2 * 3 + 0], cy = base[i2 * 3 + 1], cz = base[i2 * 3 + 2];
        float e1x = bx - ax, e1y = by - ay, e1z = bz - az;
        float e2x = cx - ax, e2y = cy - ay, e2z = cz - az;
        sx += e1y * e2z - e1z * e2y;
        sy += e1z * e2x - e1x * e2z;
        sz += e1x * e2y - e1y * e2x;
    }
    size_t o = ((size_t)b * kV + v) * 3;
    nrm[o + 0] = sx;
    nrm[o + 1] = sy;
    nrm[o + 2] = sz;
}

// ---------------------------------------------------------------------------
// Kernel 4: finalize per (b, n).
// ---------------------------------------------------------------------------
__global__ void finalize_kernel(const float* __restrict__ Vw,
                                const float* __restrict__ nrm,
                                const int* __restrict__ vidx,
                                const float* __restrict__ poff,
                                const float* __restrict__ craw,
                                const float* __restrict__ oraw,
                                const float* __restrict__ lsc,
                                const float* __restrict__ quat,
                                float* __restrict__ out) {
    int b = blockIdx.y;
    int n = blockIdx.x * blockDim.x + threadIdx.x;
    if (n >= kN) return;

    int vi = vidx[n];
    size_t vo = ((size_t)b * kV + vi) * 3;
    float bx = Vw[vo + 0], by = Vw[vo + 1], bz = Vw[vo + 2];

    float nx0 = nrm[vo + 0], ny0 = nrm[vo + 1], nz0 = nrm[vo + 2];
    float ninv = rsqrtf(nx0 * nx0 + ny0 * ny0 + nz0 * nz0 + 1e-12f);
    float nx = nx0 * ninv, ny = ny0 * ninv, nz = nz0 * ninv;

    bool small = fabsf(nx) < 0.9f;
    float refx = small ? 1.0f : 0.0f;
    float refz = small ? 0.0f : 1.0f;
    float d = refx * nx + refz * nz;
    float tx0 = refx - d * nx, ty0 = -d * ny, tz0 = refz - d * nz;
    float tinv = rsqrtf(tx0 * tx0 + ty0 * ty0 + tz0 * tz0 + 1e-12f);
    float tx = tx0 * tinv, ty = ty0 * tinv, tz = tz0 * tinv;

    float btx = ny * tz - nz * ty;
    float bty = nz * tx - nx * tz;
    float btz = nx * ty - ny * tx;

    float o0 = poff[n * 3 + 0], o1 = poff[n * 3 + 1], o2 = poff[n * 3 + 2];
    float mx = bx + o0 * tx + o1 * btx + o2 * nx;
    float my = by + o0 * ty + o1 * bty + o2 * ny;
    float mz = bz + o0 * tz + o1 * btz + o2 * nz;

    float r00 = tx, r01 = btx, r02 = nx;
    float r10 = ty, r11 = bty, r12 = ny;
    float r20 = tz, r21 = btz, r22 = nz;
    float tr = r00 + r11 + r22;
    float q0, q1, q2, q3;
    if (tr > 0.0f) {
        float s = sqrtf(fmaxf(tr + 1.0f, kEps)) * 2.0f;
        q0 = 0.25f * s;
        q1 = (r21 - r12) / s;
        q2 = (r02 - r20) / s;
        q3 = (r10 - r01) / s;
    } else if (r00 > r11 && r00 > r22) {
        float s = sqrtf(fmaxf(1.0f + r00 - r11 - r22, kEps)) * 2.0f;
        q0 = (r21 - r12) / s;
        q1 = 0.25f * s;
        q2 = (r01 + r10) / s;
        q3 = (r02 + r20) / s;
    } else if (r11 > r22) {
        float s = sqrtf(fmaxf(1.0f + r11 - r00 - r22, kEps)) * 2.0f;
        q0 = (r02 - r20) / s;
        q1 = (r01 + r10) / s;
        q2 = 0.25f * s;
        q3 = (r12 + r21) / s;
    } else {
        float s = sqrtf(fmaxf(1.0f + r22 - r00 - r11, kEps)) * 2.0f;
        q0 = (r10 - r01) / s;
        q1 = (r02 + r20) / s;
        q2 = (r12 + r21) / s;
        q3 = 0.25f * s;
    }
    float qinv = rsqrtf(q0 * q0 + q1 * q1 + q2 * q2 + q3 * q3 + 1e-12f);
    q0 *= qinv; q1 *= qinv; q2 *= qinv; q3 *= qinv;

    float lw = quat[(size_t)n * 4 + 0];
    float lx = quat[(size_t)n * 4 + 1];
    float ly = quat[(size_t)n * 4 + 2];
    float lz = quat[(size_t)n * 4 + 3];
    float linv = rsqrtf(lw * lw + lx * lx + ly * ly + lz * lz + 1e-12f);
    lw *= linv; lx *= linv; ly *= linv; lz *= linv;

    float rw = q0 * lw - q1 * lx - q2 * ly - q3 * lz;
    float rx = q0 * lx + q1 * lw + q2 * lz - q3 * ly;
    float ry = q0 * ly - q1 * lz + q2 * lw + q3 * lx;
    float rz = q0 * lz + q1 * ly - q2 * lx + q3 * lw;

    float c0 = 1.0f / (1.0f + expf(-craw[n * 3 + 0]));
    float c1 = 1.0f / (1.0f + expf(-craw[n * 3 + 1]));
    float c2 = 1.0f / (1.0f + expf(-craw[n * 3 + 2]));
    float op = 1.0f / (1.0f + expf(-oraw[n]));
    float s0 = fminf(fmaxf(expf(lsc[n * 3 + 0]), 0.0005f), 0.05f);
    float s1 = fminf(fmaxf(expf(lsc[n * 3 + 1]), 0.0005f), 0.05f);
    float s2 = fminf(fmaxf(expf(lsc[n * 3 + 2]), 0.0005f), 0.05f);

    size_t bn = (size_t)b * kN + n;
    out[OFF_MEANS + bn * 3 + 0] = mx;
    out[OFF_MEANS + bn * 3 + 1] = my;
    out[OFF_MEANS + bn * 3 + 2] = mz;
    out[OFF_COLORS + bn * 3 + 0] = c0;
    out[OFF_COLORS + bn * 3 + 1] = c1;
    out[OFF_COLORS + bn * 3 + 2] = c2;
    out[OFF_OPAC + bn] = op;
    out[OFF_SCALE + bn * 3 + 0] = s0;
    out[OFF_SCALE + bn * 3 + 1] = s1;
    out[OFF_SCALE + bn * 3 + 2] = s2;
    out[OFF_ROT + bn * 4 + 0] = rw;
    out[OFF_ROT + bn * 4 + 1] = rx;
    out[OFF_ROT + bn * 4 + 2] = ry;
    out[OFF_ROT + bn * 4 + 3] = rz;
}

extern "C" void kernel_launch(void* const* d_in, const int* in_sizes, int n_in,
                              void* d_out, int out_size, void* d_ws, size_t ws_size,
                              hipStream_t stream) {
    const float* pose  = (const float*)d_in[0];
    const float* trans = (const float*)d_in[1];
    const float* scale = (const float*)d_in[2];
    const float* vt    = (const float*)d_in[3];
    const float* sw    = (const float*)d_in[4];
    const float* jr    = (const float*)d_in[5];
    const float* poff  = (const float*)d_in[6];
    const float* craw  = (const float*)d_in[7];
    const float* oraw  = (const float*)d_in[8];
    const float* lsc   = (const float*)d_in[9];
    const float* quat  = (const float*)d_in[10];
    const int*   vidx  = (const int*)d_in[11];
    const int*   faces = (const int*)d_in[12];
    float* out = (float*)d_out;

    char* ws = (char*)d_ws;
    float* A       = (float*)(ws + WS_A);
    float* Vw      = (float*)(ws + WS_VW);
    float* nrm     = (float*)(ws + WS_NRM);
    int*   cnt     = (int*)(ws + WS_CNT);
    int*   offs    = (int*)(ws + WS_OFFS);
    int*   entries = (int*)(ws + WS_ENTRIES);

    // --- CSR adjacency build (batch-independent) ---
    hipMemsetAsync(cnt, 0, kV * sizeof(int), stream);
    count_kernel<<<(kF + 255) / 256, 256, 0, stream>>>(faces, cnt);
    scan_kernel<<<1, 1024, 0, stream>>>(cnt, offs);
    hipMemsetAsync(cnt, 0, kV * sizeof(int), stream);  // reuse as fill cursor
    fill_kernel<<<(kF + 255) / 256, 256, 0, stream>>>(faces, offs, cnt, entries);

    // --- joint chain + skinning ---
    jt_kernel<<<1, 64, 0, stream>>>(pose, jr, A);
    dim3 g2((kV + 255) / 256, kB);
    skin_kernel<<<g2, 256, 0, stream>>>(A, sw, vt, scale, trans, Vw);

    // --- vertex normals: dense gather, no atomics ---
    dim3 g3((kV + 255) / 256, kB);
    gather_normals_kernel<<<g3, 256, 0, stream>>>(Vw, faces, offs, entries, nrm);

    // --- finalize ---
    dim3 g4((kN + 255) / 256, kB);
    finalize_kernel<<<g4, 256, 0, stream>>>(Vw, nrm, vidx, poff, craw, oraw,
                                            lsc, quat, out);
}